// Round 8
// baseline (802.767 us; speedup 1.0000x reference)
//
#include <hip/hip_runtime.h>
#include <math.h>

// PnPNystra attention, MFMA v6: fused-pair phases in E and F (~37 barriers vs 47),
// 1024-thr / 16-wave k_main, register-cached fragments, 16 LDS planes.
// G=4096 groups (B*H), N=256, d=64, L=64.
// All 64x64 matrices in LDS as SPLIT f16: v ~= h + l/2048 (lo pre-scaled by
// 2048 -> f16 normal range). Matmul = 3x mfma_f32_16x16x32_f16 (hh, h*l, l*h),
// fp32 accumulate -> ~2^-21 product error. Z (NS iterate) scaled by 1024.

#define G_TOT 4096
#define TPB_R 256
#define TPB_M 1024
typedef _Float16 f16;
typedef __attribute__((ext_vector_type(2))) _Float16 f16x2;
typedef __attribute__((ext_vector_type(4))) _Float16 f16x4;
typedef __attribute__((ext_vector_type(8))) _Float16 f16x8;
typedef __attribute__((ext_vector_type(4))) float f32x4;
typedef __attribute__((ext_vector_type(16))) float f32x16;

#define NPLANES 16
#define SMEM_BYTES (NPLANES * 4096 * 2 + 320 * 4)  // 132352 B

#define LSCALE 2048.0f
#define LINV   (1.0f / 2048.0f)
#define ZS     1024.0f
#define ZINV   (1.0f / 1024.0f)

struct HL { f16 h, l; };
__device__ __forceinline__ HL split2(float v) {
    HL r;
    r.h = (f16)v;
    r.l = (f16)((v - (float)r.h) * LSCALE);
    return r;
}
__device__ __forceinline__ float join2(f16 h, f16 l) {
    return (float)h + (float)l * LINV;
}
__device__ __forceinline__ int swi(int r, int c) {
    return (r << 6) + (c ^ ((r & 7) << 3));
}
__device__ __forceinline__ float activ_f(float x) {          // k_main fast path
    return __expf(fminf(x, 5.0f)) + fmaxf(x - 5.0f, 0.0f);
}
__device__ __forceinline__ float activ_r(float x) {          // k_reduce (unchanged)
    return expf(fminf(x, 5.0f)) + fmaxf(x - 5.0f, 0.0f);
}
__device__ __forceinline__ void split_w(f16* Ph, f16* Pl, int r, int c, float v) {
    HL s = split2(v);
    const int o = swi(r, c);
    Ph[o] = s.h;
    Pl[o] = s.l;
}
__device__ __forceinline__ f16x2 mk2(f16 a, f16 b) { f16x2 r; r[0]=a; r[1]=b; return r; }
__device__ __forceinline__ f16x4 mk4(f16 a, f16 b, f16 c, f16 d) { f16x4 r; r[0]=a;r[1]=b;r[2]=c;r[3]=d; return r; }
__device__ __forceinline__ f32x4 z4() { f32x4 z = {0.f,0.f,0.f,0.f}; return z; }
__device__ __forceinline__ f32x16 z16() {
    f32x16 z;
#pragma unroll
    for (int i = 0; i < 16; ++i) z[i] = 0.f;
    return z;
}

// ---- fragment container: one 16-row operand stripe for 16x16x32 MFMA ----
struct Frag { f16x8 h[2], l[2]; };

__device__ __forceinline__ Frag ld_frag(const f16* __restrict__ Ph,
                                        const f16* __restrict__ Pl,
                                        int row, int kg) {
    Frag f;
    const int base = row << 6, x = (row & 7) << 3;
#pragma unroll
    for (int s = 0; s < 2; ++s) {
        const int o = base + ((((s << 5) + (kg << 3))) ^ x);
        f.h[s] = *(const f16x8*)(Ph + o);
        f.l[s] = *(const f16x8*)(Pl + o);
    }
    return f;
}

// C_tile += A*B, 3-term split, both operands as register fragments.
__device__ __forceinline__ f32x4 mm16_rr(const Frag& A, const Frag& B, f32x4 acc) {
    f32x4 ax1 = z4(), ax2 = z4();
#pragma unroll
    for (int s = 0; s < 2; ++s) {
        acc = __builtin_amdgcn_mfma_f32_16x16x32_f16(A.h[s], B.h[s], acc, 0, 0, 0);
        ax1 = __builtin_amdgcn_mfma_f32_16x16x32_f16(A.h[s], B.l[s], ax1, 0, 0, 0);
        ax2 = __builtin_amdgcn_mfma_f32_16x16x32_f16(A.l[s], B.h[s], ax2, 0, 0, 0);
    }
    acc += (ax1 + ax2) * LINV;
    return acc;
}

// fragment writes: values v[m] live at (Rb+m, C)
__device__ __forceinline__ void wfrag_rm(f16* Ph, f16* Pl, int Rb, int C, const float* v) {
#pragma unroll
    for (int m = 0; m < 4; ++m) split_w(Ph, Pl, Rb + m, C, v[m]);
}
// transposed-layout write: plane[C][Rb..Rb+3] <- v[0..3]  (contiguous under swizzle)
__device__ __forceinline__ void wfrag_t(f16* Ph, f16* Pl, int Rb, int C, const float* v) {
    const int o = swi(C, Rb);
    HL s0 = split2(v[0]), s1 = split2(v[1]), s2 = split2(v[2]), s3 = split2(v[3]);
    *(f16x4*)(Ph + o) = mk4(s0.h, s1.h, s2.h, s3.h);
    *(f16x4*)(Pl + o) = mk4(s0.l, s1.l, s2.l, s3.l);
}

// ---- staging helpers (1024 threads) ----
__device__ __forceinline__ void wr_rm(float4 vv, f16* Ph, f16* Pl, int t) {
    const int r = t >> 4, c4 = (t & 15) << 2;
    const int o = swi(r, c4);
    HL s0 = split2(vv.x), s1 = split2(vv.y), s2 = split2(vv.z), s3 = split2(vv.w);
    *(f16x4*)(Ph + o) = mk4(s0.h, s1.h, s2.h, s3.h);
    *(f16x4*)(Pl + o) = mk4(s0.l, s1.l, s2.l, s3.l);
}
__device__ __forceinline__ void ld_vt(const float* __restrict__ src, int t,
                                      float2& va, float2& vb) {
    const int n0 = (t >> 5) << 1, e0 = (t & 31) << 1;
    va = *(const float2*)(src + (size_t)n0 * 64 + e0);
    vb = *(const float2*)(src + (size_t)(n0 + 1) * 64 + e0);
}
__device__ __forceinline__ void wr_vt(float2 va, float2 vb, f16* Ph, f16* Pl, int t) {
    const int n0 = (t >> 5) << 1, e0 = (t & 31) << 1;
    HL ax = split2(va.x), ay = split2(va.y), bx = split2(vb.x), by = split2(vb.y);
    const int o0 = swi(e0, n0), o1 = swi(e0 + 1, n0);
    *(f16x2*)(Ph + o0) = mk2(ax.h, bx.h);
    *(f16x2*)(Pl + o0) = mk2(ax.l, bx.l);
    *(f16x2*)(Ph + o1) = mk2(ay.h, by.h);
    *(f16x2*)(Pl + o1) = mk2(ay.l, by.l);
}

// pool 2x2-mean landmarks from global fp32 [256][64] -> split planes [64][64]
__device__ __forceinline__ void pool_global1024(const float* __restrict__ src,
                                                f16* Ph, f16* Pl, int t) {
    const int L = t >> 4, d0 = (t & 15) << 2;
    const int nb = ((L >> 3) << 5) + ((L & 7) << 1);
    const float* p = src + (size_t)nb * 64 + d0;
    float4 a = *(const float4*)p;
    float4 b = *(const float4*)(p + 64);
    float4 c = *(const float4*)(p + 1024);
    float4 d = *(const float4*)(p + 1088);
    HL s0 = split2(0.25f * (a.x + b.x + c.x + d.x));
    HL s1 = split2(0.25f * (a.y + b.y + c.y + d.y));
    HL s2 = split2(0.25f * (a.z + b.z + c.z + d.z));
    HL s3 = split2(0.25f * (a.w + b.w + c.w + d.w));
    const int o = swi(L, d0);
    *(f16x4*)(Ph + o) = mk4(s0.h, s1.h, s2.h, s3.h);
    *(f16x4*)(Pl + o) = mk4(s0.l, s1.l, s2.l, s3.l);
}

// pool landmarks of one staged K tile (tile tt) into KM planes (t in [0,512))
__device__ __forceinline__ void pool_lds512(const f16* Kh, const f16* Kl,
                                            f16* Ph, f16* Pl, int t, int tt) {
    const int ll = t >> 5, d0 = (t & 31) << 1;
    const int rb = ((ll >> 3) << 5) + ((ll & 7) << 1);
    float s0 = 0.f, s1 = 0.f;
#pragma unroll
    for (int rr = 0; rr < 4; ++rr) {
        const int r = rb + (rr & 1) + ((rr >> 1) << 4);
        const int o = swi(r, d0);
        f16x2 h = *(const f16x2*)(Kh + o);
        f16x2 l = *(const f16x2*)(Kl + o);
        s0 += join2(h[0], l[0]);
        s1 += join2(h[1], l[1]);
    }
    const int L = (tt << 4) + ll;
    HL p0 = split2(0.25f * s0), p1 = split2(0.25f * s1);
    const int o = swi(L, d0);
    *(f16x2*)(Ph + o) = mk2(p0.h, p1.h);
    *(f16x2*)(Pl + o) = mk2(p0.l, p1.l);
}

// ---- k_reduce helpers (unchanged) ----
__device__ __forceinline__ f32x16 mm64q(const f16* __restrict__ Ah, const f16* __restrict__ Al,
                                        const f16* __restrict__ Bh, const f16* __restrict__ Bl,
                                        int lane, int wr, int wc, f32x16 acc) {
    const int cl = lane & 31, hh = lane >> 5;
    const int ar = (wr << 5) + cl, br = (wc << 5) + cl;
    const int abase = ar << 6, axor = (ar & 7) << 3;
    const int bbase = br << 6, bxor = (br & 7) << 3;
    f32x16 ax1 = z16();
    f32x16 ax2 = z16();
#pragma unroll
    for (int ks = 0; ks < 4; ++ks) {
        const int k0 = (ks << 4) + (hh << 3);
        const int ao = abase + (k0 ^ axor);
        const int bo = bbase + (k0 ^ bxor);
        f16x8 a_h = *(const f16x8*)(Ah + ao);
        f16x8 a_l = *(const f16x8*)(Al + ao);
        f16x8 b_h = *(const f16x8*)(Bh + bo);
        f16x8 b_l = *(const f16x8*)(Bl + bo);
        acc = __builtin_amdgcn_mfma_f32_32x32x16_f16(a_h, b_h, acc, 0, 0, 0);
        ax1 = __builtin_amdgcn_mfma_f32_32x32x16_f16(a_h, b_l, ax1, 0, 0, 0);
        ax2 = __builtin_amdgcn_mfma_f32_32x32x16_f16(a_l, b_h, ax2, 0, 0, 0);
    }
    acc += (ax1 + ax2) * LINV;
    return acc;
}
__device__ __forceinline__ void pool_global_r(const float* __restrict__ src,
                                              f16* Ph, f16* Pl, int t) {
    const int ll = t >> 4, d0 = (t & 15) << 2;
    const int rb = ((ll >> 3) << 5) + ((ll & 7) << 1);
#pragma unroll
    for (int tt = 0; tt < 4; ++tt) {
        const float* p = src + (size_t)((tt << 6) + rb) * 64 + d0;
        float4 a = *(const float4*)p;
        float4 b = *(const float4*)(p + 64);
        float4 c = *(const float4*)(p + 1024);
        float4 d = *(const float4*)(p + 1088);
        const int L = (tt << 4) + ll;
        split_w(Ph, Pl, L, d0 + 0, 0.25f * (a.x + b.x + c.x + d.x));
        split_w(Ph, Pl, L, d0 + 1, 0.25f * (a.y + b.y + c.y + d.y));
        split_w(Ph, Pl, L, d0 + 2, 0.25f * (a.z + b.z + c.z + d.z));
        split_w(Ph, Pl, L, d0 + 3, 0.25f * (a.w + b.w + c.w + d.w));
    }
}

#define WAVE_SUM32(v)            \
    v += __shfl_xor(v, 1);       \
    v += __shfl_xor(v, 2);       \
    v += __shfl_xor(v, 4);       \
    v += __shfl_xor(v, 8);       \
    v += __shfl_xor(v, 16);

__global__ void k_init(float* ws) {
    if (threadIdx.x < 2) ws[threadIdx.x] = 0.0f;
}

// global max of row/col sums of activ(QM @ KM^T) over all groups (unchanged)
__global__ __launch_bounds__(TPB_R) void k_reduce(const float* __restrict__ q,
                                                  const float* __restrict__ k,
                                                  float* __restrict__ ws) {
    __shared__ f16 pls[4 * 4096];
    __shared__ float rowS[64], colS[64];
    const int t = threadIdx.x, g = blockIdx.x;
    const int lane = t & 63, wv = t >> 6, wr = wv >> 1, wc = wv & 1;
    const int cl = lane & 31, hh = lane >> 5;
    if (t < 64) rowS[t] = 0.f;
    else if (t < 128) colS[t - 64] = 0.f;
    pool_global_r(q + (size_t)g * 16384, pls, pls + 4096, t);
    pool_global_r(k + (size_t)g * 16384, pls + 8192, pls + 12288, t);
    __syncthreads();
    f32x16 a = mm64q(pls, pls + 4096, pls + 8192, pls + 12288, lane, wr, wc, z16());
    float colp = 0.f;
#pragma unroll
    for (int m = 0; m < 16; ++m) {
        float x = activ_r(a[m]);
        const int R = (wr << 5) + (m & 3) + ((m >> 2) << 3) + (hh << 2);
        float vs = x;
        WAVE_SUM32(vs)
        if (cl == 0) atomicAdd(&rowS[R], vs);
        colp += x;
    }
    colp += __shfl_xor(colp, 32);
    if (hh == 0) atomicAdd(&colS[(wc << 5) + cl], colp);
    __syncthreads();
    if (t < 64) {
        float vmx = rowS[t];
        for (int off = 1; off < 64; off <<= 1) vmx = fmaxf(vmx, __shfl_xor(vmx, off));
        if (t == 0) atomicMax((int*)ws, __float_as_int(vmx));
    } else if (t < 128) {
        float vmx = colS[t - 64];
        for (int off = 1; off < 64; off <<= 1) vmx = fmaxf(vmx, __shfl_xor(vmx, off));
        if (t == 64) atomicMax(((int*)ws) + 1, __float_as_int(vmx));
    }
}

// ============================ k_main (v6) ============================
// Logical plane pairs: P0=X, P1=SA, P2=SB, P3=KM, P4=SC, P5=KV, P6=Zr, P7=Zt.
// E (fused 2 tiles/phase): K-tiles in P1/P4, V^T-tiles in P2/P0, S-tiles in P7/P5.
// D: gens ping-pong (P6,P7)<->(P1,P4); T2 in P0; oT in P2.
// F (fused): q-stage P1/P4 (then P2/P0), qk P2/P0 (then P1/P4), w P1/P4 (then P2/P0).
__global__ __launch_bounds__(TPB_M, 4) void k_main(const float* __restrict__ q,
                                                   const float* __restrict__ k,
                                                   const float* __restrict__ v,
                                                   const float* __restrict__ ws,
                                                   float* __restrict__ out) {
    extern __shared__ f16 smu[];
    float* kv1 = (float*)(smu + NPLANES * 4096);
    float* den = kv1 + 64;  // den[4][64]
    const int t = threadIdx.x, g = blockIdx.x;
    const int lane = t & 63, w = t >> 6;
    const int ti = w & 3, tj = w >> 2;
    const int fr = lane & 15, kg = lane >> 4;
    const int arow = (ti << 4) + fr;
    const int brow = (tj << 4) + fr;
    const int C = brow;
    const int Rb = (ti << 4) + (kg << 2);
    const float* Gq = q + (size_t)g * 16384;
    const float* Gk = k + (size_t)g * 16384;
    const float* Gv = v + (size_t)g * 16384;
    float* og = out + (size_t)g * 16384;

    f16* Xh  = smu +  0 * 4096; f16* Xl  = smu +  1 * 4096;  // P0
    f16* SAh = smu +  2 * 4096; f16* SAl = smu +  3 * 4096;  // P1
    f16* SBh = smu +  4 * 4096; f16* SBl = smu +  5 * 4096;  // P2
    f16* KMh = smu +  6 * 4096; f16* KMl = smu +  7 * 4096;  // P3
    f16* SCh = smu +  8 * 4096; f16* SCl = smu +  9 * 4096;  // P4
    f16* KVh = smu + 10 * 4096; f16* KVl = smu + 11 * 4096;  // P5
    f16* Zrh = smu + 12 * 4096; f16* Zrl = smu + 13 * 4096;  // P6
    f16* Zth = smu + 14 * 4096; f16* Ztl = smu + 15 * 4096;  // P7

    // ---- prologue: QM->P6; K0->P1, K1->P4; V0t->P2, V1t->P0; zero sums ----
    if (t < 320) kv1[t] = 0.f;
    pool_global1024(Gq, Zrh, Zrl, t);
    {
        float4 k0 = *(const float4*)(Gk + (size_t)t * 4);
        float4 k1 = *(const float4*)(Gk + 4096 + (size_t)t * 4);
        float2 va0, vb0, va1, vb1;
        ld_vt(Gv, t, va0, vb0);
        ld_vt(Gv + 4096, t, va1, vb1);
        wr_rm(k0, SAh, SAl, t);
        wr_rm(k1, SCh, SCl, t);
        wr_vt(va0, vb0, SBh, SBl, t);
        wr_vt(va1, vb1, Xh, Xl, t);
    }
    __syncthreads();

    Frag fQM = ld_frag(Zrh, Zrl, arow, kg);   // QM A-frag, cached for E and B

    // ---- phase E (fused pairs): KV = activ(QM@K^T)@V ; pool KM; kv1 sums ----
    f32x4 kva = z4();
    float4 kr2 = *(const float4*)(Gk + 2 * 4096 + (size_t)t * 4);
    float4 kr3 = *(const float4*)(Gk + 3 * 4096 + (size_t)t * 4);
    // e-a: pool KM(0,1); S0=activ(QM@K0^T)->P7, S1->P5; kv1
    if (t < 512) pool_lds512(SAh, SAl, KMh, KMl, t, 0);
    else         pool_lds512(SCh, SCl, KMh, KMl, t - 512, 1);
    {
        Frag b0 = ld_frag(SAh, SAl, brow, kg);
        Frag b1 = ld_frag(SCh, SCl, brow, kg);
        f32x4 s0 = mm16_rr(fQM, b0, z4());
        f32x4 s1 = mm16_rr(fQM, b1, z4());
        float sv0[4], sv1[4];
#pragma unroll
        for (int m = 0; m < 4; ++m) {
            sv0[m] = activ_f(s0[m]);
            sv1[m] = activ_f(s1[m]);
            float vs = sv0[m] + sv1[m];
            vs += __shfl_xor(vs, 1); vs += __shfl_xor(vs, 2);
            vs += __shfl_xor(vs, 4); vs += __shfl_xor(vs, 8);
            if (fr == 0) atomicAdd(&kv1[Rb + m], vs);
        }
        wfrag_rm(Zth, Ztl, Rb, C, sv0);   // S0 -> P7
        wfrag_rm(KVh, KVl, Rb, C, sv1);   // S1 -> P5
    }
    __syncthreads();
    // e-b: KV += S0@V0t + S1@V1t ; stage K2->P1, K3->P4; issue V2,V3 loads
    float2 va2, vb2, va3, vb3;
    ld_vt(Gv + 2 * 4096, t, va2, vb2);
    ld_vt(Gv + 3 * 4096, t, va3, vb3);
    {
        Frag a0 = ld_frag(Zth, Ztl, arow, kg);
        Frag b0 = ld_frag(SBh, SBl, brow, kg);
        kva = mm16_rr(a0, b0, kva);
        Frag a1 = ld_frag(KVh, KVl, arow, kg);
        Frag b1 = ld_frag(Xh, Xl, brow, kg);
        kva = mm16_rr(a1, b1, kva);
    }
    wr_rm(kr2, SAh, SAl, t);
    wr_rm(kr3, SCh, SCl, t);
    __syncthreads();
    // e-c: pool KM(2,3); S2->P7, S3->P5; stage V2t->P2, V3t->P0; kv1
    if (t < 512) pool_lds512(SAh, SAl, KMh, KMl, t, 2);
    else         pool_lds512(SCh, SCl, KMh, KMl, t - 512, 3);
    {
        Frag b0 = ld_frag(SAh, SAl, brow, kg);
        Frag b1 = ld_frag(SCh, SCl, brow, kg);
        f32x4 s0 = mm16_rr(fQM, b0, z4());
        f32x4 s1 = mm16_rr(fQM, b1, z4());
        float sv0[4], sv1[4];
#pragma unroll
        for (int m = 0; m < 4; ++m) {
            sv0[m] = activ_f(s0[m]);
            sv1[m] = activ_f(s1[m]);
            float vs = sv0[m] + sv1[m];
            vs += __shfl_xor(vs, 1); vs += __shfl_xor(vs, 2);
            vs += __shfl_xor(vs, 4); vs += __shfl_xor(vs, 8);
            if (fr == 0) atomicAdd(&kv1[Rb + m], vs);
        }
        wfrag_rm(Zth, Ztl, Rb, C, sv0);
        wfrag_rm(KVh, KVl, Rb, C, sv1);
    }
    wr_vt(va2, vb2, SBh, SBl, t);
    wr_vt(va3, vb3, Xh, Xl, t);
    __syncthreads();
    // e-d: KV += S2@V2t + S3@V3t
    {
        Frag a0 = ld_frag(Zth, Ztl, arow, kg);
        Frag b0 = ld_frag(SBh, SBl, brow, kg);
        kva = mm16_rr(a0, b0, kva);
        Frag a1 = ld_frag(KVh, KVl, arow, kg);
        Frag b1 = ld_frag(Xh, Xl, brow, kg);
        kva = mm16_rr(a1, b1, kva);
    }
    __syncthreads();

    // ---- phase B: KV store (T-layout)->P5; X=activ(QM@KM^T)->P0; Z-init->P6,P7 ----
    {
        float kvv[4] = {kva[0], kva[1], kva[2], kva[3]};
        wfrag_t(KVh, KVl, Rb, C, kvv);
        Frag fKMb = ld_frag(KMh, KMl, brow, kg);
        f32x4 x0 = mm16_rr(fQM, fKMb, z4());
        const float scale = ZS / (ws[0] * ws[1] + 1e-15f);
        float xv[4], zv[4];
#pragma unroll
        for (int m = 0; m < 4; ++m) { xv[m] = activ_f(x0[m]); zv[m] = xv[m] * scale; }
        wfrag_rm(Xh, Xl, Rb, C, xv);
        wfrag_t (Zrh, Zrl, Rb, C, zv);   // Z row-major
        wfrag_rm(Zth, Ztl, Rb, C, zv);   // Z^T (B-layout)
    }
    __syncthreads();

    // ---- phase D: 6 Newton-Schulz iterations, gen ping-pong, 4 barriers/iter ----
    Frag fX = ld_frag(Xh, Xl, arow, kg);
    f16 *zrh = Zrh, *zrl = Zrl, *zth = Zth, *ztl = Ztl;
    f16 *nrh = SAh, *nrl = SAl, *nth = SCh, *ntl = SCl;
#pragma unroll
    for (int it = 0; it < 6; ++it) {
        // T1 = X @ Z  (acc carries ZS)
        Frag bz = ld_frag(zth, ztl, brow, kg);
        f32x4 a1 = mm16_rr(fX, bz, z4());
        float t1k[4];
#pragma unroll
        for (int m = 0; m < 4; ++m) t1k[m] = a1[m] * ZINV;
        wfrag_rm(nrh, nrl, Rb, C, t1k);
        wfrag_t (nth, ntl, Rb, C, t1k);
        __syncthreads();
        // T2 = T1 @ T1
        Frag aT1 = ld_frag(nrh, nrl, arow, kg);
        Frag bT1 = ld_frag(nth, ntl, brow, kg);
        f32x4 a2 = mm16_rr(aT1, bT1, z4());
        float t2k[4];
#pragma unroll
        for (int m = 0; m < 4; ++m) t2k[m] = a2[m];
        wfrag_rm(Xh, Xl, Rb, C, t2k);
        __syncthreads();
        // T4 = T2 @ T1 ; outer = 13I - 15 T1 + 7 T2 - T4 (own frags in regs)
        Frag aT2 = ld_frag(Xh, Xl, arow, kg);
        f32x4 a3 = mm16_rr(aT2, bT1, z4());
        float ov[4];
#pragma unroll
        for (int m = 0; m < 4; ++m) {
            const int R = Rb + m;
            ov[m] = ((R == C) ? 13.f : 0.f) - 15.f * t1k[m] + 7.f * t2k[m] - a3[m];
        }
        wfrag_t(SBh, SBl, Rb, C, ov);
        __syncthreads();
        // Znew = 0.25 * Z @ outer
        Frag aZ = ld_frag(zrh, zrl, arow, kg);
        Frag bO = ld_frag(SBh, SBl, brow, kg);
        f32x4 a4 = mm16_rr(aZ, bO, z4());
        float zk[4];
#pragma unroll
        for (int m = 0; m < 4; ++m) zk[m] = 0.25f * a4[m];
        wfrag_rm(nrh, nrl, Rb, C, zk);
        wfrag_t (nth, ntl, Rb, C, zk);
        __syncthreads();
        f16* tp;
        tp = zrh; zrh = nrh; nrh = tp;  tp = zrl; zrl = nrl; nrl = tp;
        tp = zth; zth = nth; nth = tp;  tp = ztl; ztl = ntl; ntl = tp;
    }
    // final Z: Zr=P6, Zt=P7

    // ---- phase F (fused pairs): out = (activ(q@KM^T) @ Z @ KV) / den ----
    // f-stage: q0->P1, q1->P4; cache B-frags
    {
        float4 q0 = *(const float4*)(Gq + (size_t)t * 4);
        float4 q1 = *(const float4*)(Gq + 4096 + (size_t)t * 4);
        wr_rm(q0, SAh, SAl, t);
        wr_rm(q1, SCh, SCl, t);
    }
    Frag fKM = ld_frag(KMh, KMl, brow, kg);
    Frag fZt = ld_frag(Zth, Ztl, brow, kg);
    Frag fKV = ld_frag(KVh, KVl, brow, kg);
    const float kvC = kv1[C];
    float4 qr2 = *(const float4*)(Gq + 2 * 4096 + (size_t)t * 4);
    float4 qr3 = *(const float4*)(Gq + 3 * 4096 + (size_t)t * 4);
    __syncthreads();
    // f-A: qk0 = activ(P1@fKM)->P2; qk1 = activ(P4@fKM)->P0
    {
        Frag a0 = ld_frag(SAh, SAl, arow, kg);
        Frag a1 = ld_frag(SCh, SCl, arow, kg);
        f32x4 r0 = mm16_rr(a0, fKM, z4());
        f32x4 r1 = mm16_rr(a1, fKM, z4());
        float qv0[4], qv1[4];
#pragma unroll
        for (int m = 0; m < 4; ++m) { qv0[m] = activ_f(r0[m]); qv1[m] = activ_f(r1[m]); }
        wfrag_rm(SBh, SBl, Rb, C, qv0);
        wfrag_rm(Xh, Xl, Rb, C, qv1);
    }
    __syncthreads();
    // f-B: w0 = P2@fZt->P1; w1 = P0@fZt->P4; den tiles 0,1
    {
        Frag a0 = ld_frag(SBh, SBl, arow, kg);
        Frag a1 = ld_frag(Xh, Xl, arow, kg);
        f32x4 w0 = mm16_rr(a0, fZt, z4());
        f32x4 w1 = mm16_rr(a1, fZt, z4());
        float wv0[4], wv1[4];
#pragma unroll
        for (int m = 0; m < 4; ++m) {
            wv0[m] = w0[m] * ZINV;
            wv1[m] = w1[m] * ZINV;
            float d0_ = wv0[m] * kvC;
            d0_ += __shfl_xor(d0_, 1); d0_ += __shfl_xor(d0_, 2);
            d0_ += __shfl_xor(d0_, 4); d0_ += __shfl_xor(d0_, 8);
            if (fr == 0) atomicAdd(&den[Rb + m], d0_);
            float d1_ = wv1[m] * kvC;
            d1_ += __shfl_xor(d1_, 1); d1_ += __shfl_xor(d1_, 2);
            d1_ += __shfl_xor(d1_, 4); d1_ += __shfl_xor(d1_, 8);
            if (fr == 0) atomicAdd(&den[64 + Rb + m], d1_);
        }
        wfrag_rm(SAh, SAl, Rb, C, wv0);
        wfrag_rm(SCh, SCl, Rb, C, wv1);
    }
    __syncthreads();
    // f-C: prod0 = P1@fKV -> out t0; prod1 = P4@fKV -> out t1; q2->P2, q3->P0
    {
        Frag a0 = ld_frag(SAh, SAl, arow, kg);
        Frag a1 = ld_frag(SCh, SCl, arow, kg);
        f32x4 p0 = mm16_rr(a0, fKV, z4());
        f32x4 p1 = mm16_rr(a1, fKV, z4());
#pragma unroll
        for (int m = 0; m < 4; ++m) {
            const int R = Rb + m;
            og[(size_t)R * 64 + C]         = p0[m] / (den[R] + 1e-12f);
            og[(size_t)(64 + R) * 64 + C]  = p1[m] / (den[64 + R] + 1e-12f);
        }
    }
    wr_rm(qr2, SBh, SBl, t);
    wr_rm(qr3, Xh, Xl, t);
    __syncthreads();
    // f-D: qk2 = activ(P2@fKM)->P1; qk3 = activ(P0@fKM)->P4
    {
        Frag a0 = ld_frag(SBh, SBl, arow, kg);
        Frag a1 = ld_frag(Xh, Xl, arow, kg);
        f32x4 r0 = mm16_rr(a0, fKM, z4());
        f32x4 r1 = mm16_rr(a1, fKM, z4());
        float qv0[4], qv1[4];
#pragma unroll
        for (int m = 0; m < 4; ++m) { qv0[m] = activ_f(r0[m]); qv1[m] = activ_f(r1[m]); }
        wfrag_rm(SAh, SAl, Rb, C, qv0);
        wfrag_rm(SCh, SCl, Rb, C, qv1);
    }
    __syncthreads();
    // f-E: w2 = P1@fZt->P2; w3 = P4@fZt->P0; den tiles 2,3
    {
        Frag a0 = ld_frag(SAh, SAl, arow, kg);
        Frag a1 = ld_frag(SCh, SCl, arow, kg);
        f32x4 w0 = mm16_rr(a0, fZt, z4());
        f32x4 w1 = mm16_rr(a1, fZt, z4());
        float wv0[4], wv1[4];
#pragma unroll
        for (int m = 0; m < 4; ++m) {
            wv0[m] = w0[m] * ZINV;
            wv1[m] = w1[m] * ZINV;
            float d0_ = wv0[m] * kvC;
            d0_ += __shfl_xor(d0_, 1); d0_ += __shfl_xor(d0_, 2);
            d0_ += __shfl_xor(d0_, 4); d0_ += __shfl_xor(d0_, 8);
            if (fr == 0) atomicAdd(&den[128 + Rb + m], d0_);
            float d1_ = wv1[m] * kvC;
            d1_ += __shfl_xor(d1_, 1); d1_ += __shfl_xor(d1_, 2);
            d1_ += __shfl_xor(d1_, 4); d1_ += __shfl_xor(d1_, 8);
            if (fr == 0) atomicAdd(&den[192 + Rb + m], d1_);
        }
        wfrag_rm(SBh, SBl, Rb, C, wv0);
        wfrag_rm(Xh, Xl, Rb, C, wv1);
    }
    __syncthreads();
    // f-F: prod2 = P2@fKV -> out t2; prod3 = P0@fKV -> out t3
    {
        Frag a0 = ld_frag(SBh, SBl, arow, kg);
        Frag a1 = ld_frag(Xh, Xl, arow, kg);
        f32x4 p0 = mm16_rr(a0, fKV, z4());
        f32x4 p1 = mm16_rr(a1, fKV, z4());
#pragma unroll
        for (int m = 0; m < 4; ++m) {
            const int R = Rb + m;
            og[(size_t)(128 + R) * 64 + C] = p0[m] / (den[128 + R] + 1e-12f);
            og[(size_t)(192 + R) * 64 + C] = p1[m] / (den[192 + R] + 1e-12f);
        }
    }
}

extern "C" void kernel_launch(void* const* d_in, const int* in_sizes, int n_in,
                              void* d_out, int out_size, void* d_ws, size_t ws_size,
                              hipStream_t stream) {
    const float* q = (const float*)d_in[0];
    const float* k = (const float*)d_in[1];
    const float* v = (const float*)d_in[2];
    float* out = (float*)d_out;
    float* ws  = (float*)d_ws;
    (void)in_sizes; (void)n_in; (void)out_size; (void)ws_size;

    hipFuncSetAttribute((const void*)k_main,
                        hipFuncAttributeMaxDynamicSharedMemorySize, SMEM_BYTES);

    k_init<<<1, 64, 0, stream>>>(ws);
    k_reduce<<<G_TOT, TPB_R, 0, stream>>>(q, k, ws);
    k_main<<<G_TOT, TPB_M, SMEM_BYTES, stream>>>(q, k, v, ws, out);
}